// Round 2
// baseline (1659.832 us; speedup 1.0000x reference)
//
#include <hip/hip_runtime.h>
#include <stdint.h>

typedef unsigned long long u64;

#define HW 16384   // 128*128

// workspace byte offsets (total ~74 MB)
#define OFF_R      0ull           // fp32 [16][64][16384]  running r
#define OFF_SGR    67108864ull    // u64  [16][16384]  sign bits of r (bit c = r<0)
#define OFF_SGT    69206016ull    // u64  [16][16384]  sign bits of conv1 sums
#define OFF_NZT    71303168ull    // u64  [16][16384]  nonzero bits of conv1 sums
#define OFF_WBITS  73400320ull    // u64  [33][64][9]  weight sign masks over ci
#define OFF_ALPHA  73552384ull    // f32  [33][64]
#define OFF_WEFF   73560832ull    // f32  [ey3*ex3][py2][ry4][ci64][o3][px2][rx4] = 110592

// ---------------- prep: binary weight masks + alpha ----------------
__global__ __launch_bounds__(256) void k_prep_bits(const float* __restrict__ wbody, const float* __restrict__ wlast,
                                                   u64* __restrict__ wbits, float* __restrict__ alpha){
  int t = blockIdx.x*256 + threadIdx.x;
  if (t >= 33*64) return;
  int cid = t >> 6, o = t & 63;
  const float* src = (cid < 32) ? (wbody + (size_t)cid*64*64*9) : wlast;   // [o][ci][kh][kw]
  u64 bits[9] = {0,0,0,0,0,0,0,0,0};
  float s = 0.f;
  for (int ci=0; ci<64; ci++){
    #pragma unroll
    for (int tap=0; tap<9; tap++){
      float w = src[(o*64+ci)*9 + tap];
      s += fabsf(w);
      if (w < 0.f) bits[tap] |= (1ull << ci);
    }
  }
  #pragma unroll
  for (int tap=0; tap<9; tap++) wbits[(size_t)(cid*64+o)*9 + tap] = bits[tap];
  alpha[cid*64+o] = s * (1.0f/576.0f);
}

// ------- prep: composed up->shuffle->tail weights (9 edge variants) -------
// out[o, Y=2y+py, X=2x+px] = b[o] + shift[o] + sum_{ry,rx,ci} Weff * res[ci, y+(py-2)+ry, x+(px-2)+rx]
__global__ __launch_bounds__(256) void k_prep_weff(const float* __restrict__ wup, const float* __restrict__ wtail,
                                                   float* __restrict__ weff){
  int idx = blockIdx.x*256 + threadIdx.x;     // 110592 exactly
  int rx = idx & 3;
  int px = (idx >> 2) & 1;
  int base = idx >> 3;
  int o  = base % 3;
  int t2 = base / 3;
  int ci = t2 & 63;
  int ry = (t2 >> 6) & 3;
  int py = (t2 >> 8) & 1;
  int e  = t2 >> 9;            // 0..8
  int ex = e % 3, ey = e / 3;  // ey: 0=mid 1=Y0 2=Y255 ; ex: 0=X0 1=mid 2=X255
  int ry_off = (py - 2) + ry;
  int rx_off = (px - 2) + rx;
  float acc = 0.f;
  for (int dy=0; dy<3; dy++){                 // tail tap row, offset dy-1 in t-space
    if (ey==1 && dy==0) continue;             // Y=0: t row -1 padded
    if (ey==2 && dy==2) continue;             // Y=255: t row 256 padded
    int pydy = py + dy - 1;                   // -1..2
    int sy = ((pydy + 4) >> 1) - 2;           // floor((py+dy-1)/2)
    int vy = (pydy + 4) & 1;                  // parity -> pixel-shuffle sub-row
    int a = ry_off + 1 - sy;                  // up-conv kernel row
    if (a < 0 || a > 2) continue;
    for (int dx=0; dx<3; dx++){
      if (ex==0 && dx==0) continue;
      if (ex==2 && dx==2) continue;
      int pxdx = px + dx - 1;
      int sx = ((pxdx + 4) >> 1) - 2;
      int vx = (pxdx + 4) & 1;
      int b = rx_off + 1 - sx;
      if (b < 0 || b > 2) continue;
      for (int c=0; c<64; c++){
        int u = c*4 + vy*2 + vx;              // pixel_shuffle channel mapping
        acc += wtail[((o*64+c)*3+dy)*3+dx] * wup[((u*64+ci)*3+a)*3+b];
      }
    }
  }
  weff[idx] = acc;
}

// ---------------- head: (x - shift) conv 3->64, init r=h (h kept in d_out res region), pack signs ----------------
__global__ __launch_bounds__(256) void k_head(const float* __restrict__ x, const float* __restrict__ wh,
                                              float* __restrict__ r, float* __restrict__ h, u64* __restrict__ sgR){
  __shared__ float wl[64*27];
  for (int j=threadIdx.x; j<64*27; j+=256) wl[j] = wh[j];   // [o][c][tap]
  __syncthreads();
  const int id = blockIdx.x*256 + threadIdx.x;    // 262144
  const int n = id >> 14, p = id & 16383;
  const int yy = p >> 7, xx = p & 127;
  float xv[27];
  const float sh[3] = {114.444f, 111.4605f, 103.02f};   // 255 * RGB_MEAN
  #pragma unroll
  for (int tap=0; tap<9; tap++){
    int Yq = yy + tap/3 - 1, Xq = xx + tap%3 - 1;
    bool v = ((unsigned)Yq < 128u) && ((unsigned)Xq < 128u);
    int q = (Yq << 7) + Xq;
    #pragma unroll
    for (int c=0; c<3; c++)
      xv[c*9+tap] = v ? (x[(size_t)(n*3+c)*HW + q] - sh[c]) : 0.f;   // pad AFTER mean-shift = 0
  }
  u64 sg = 0;
  for (int o=0; o<64; o++){
    float acc = 0.f;
    #pragma unroll
    for (int j=0; j<27; j++) acc += wl[o*27+j] * xv[j];
    r[(size_t)(n*64+o)*HW + p] = acc;
    h[(size_t)(n*64+o)*HW + p] = acc;
    sg |= (u64)(acc < 0.f) << o;
  }
  sgR[id] = sg;
}

// ---------------- body conv1: sign(r) -> sign/nonzero of integer sums ----------------
__global__ __launch_bounds__(256) void k_conv1(const u64* __restrict__ sgR, const u64* __restrict__ wbits,
                                               u64* __restrict__ sgT, u64* __restrict__ nzT){
  __shared__ u64 wl[576];
  for (int j=threadIdx.x; j<576; j+=256) wl[j] = wbits[j];
  __syncthreads();
  const int id = blockIdx.x*256 + threadIdx.x;
  const int n = id >> 14, p = id & 16383;
  const int yy = p >> 7, xx = p & 127;
  u64 g[9], m[9];
  int Vtot = 0;
  #pragma unroll
  for (int tap=0; tap<9; tap++){
    int Yq = yy + tap/3 - 1, Xq = xx + tap%3 - 1;
    bool v = ((unsigned)Yq < 128u) && ((unsigned)Xq < 128u);
    g[tap] = v ? sgR[(n<<14) + (Yq<<7) + Xq] : 0ull;
    m[tap] = v ? ~0ull : 0ull;
    Vtot += v ? 64 : 0;
  }
  u64 sg = 0, nz = 0;
  for (int o=0; o<64; o++){
    const u64* w = &wl[o*9];
    int P = 0;
    #pragma unroll
    for (int tap=0; tap<9; tap++) P += __popcll((g[tap] ^ w[tap]) & m[tap]);
    int S = Vtot - 2*P;            // exact integer binary-conv sum; sign(tanh(alpha*S)) == sign(S)
    sg |= (u64)(S < 0) << o;
    nz |= (u64)(S != 0) << o;      // S==0 -> sign()==0 -> channel drops out of next conv
  }
  sgT[id] = sg; nzT[id] = nz;
}

// ---------------- body conv2 + residual: r += alpha * S2, repack signs ----------------
__global__ __launch_bounds__(256) void k_conv2(const u64* __restrict__ sgT, const u64* __restrict__ nzTb,
                                               const u64* __restrict__ wbits, const float* __restrict__ alpha,
                                               float* __restrict__ r, u64* __restrict__ sgR){
  __shared__ u64 wl[576];
  __shared__ float al[64];
  for (int j=threadIdx.x; j<576; j+=256) wl[j] = wbits[j];
  if (threadIdx.x < 64) al[threadIdx.x] = alpha[threadIdx.x];
  __syncthreads();
  const int id = blockIdx.x*256 + threadIdx.x;
  const int n = id >> 14, p = id & 16383;
  const int yy = p >> 7, xx = p & 127;
  u64 g[9], m[9];
  int C = 0;
  #pragma unroll
  for (int tap=0; tap<9; tap++){
    int Yq = yy + tap/3 - 1, Xq = xx + tap%3 - 1;
    bool v = ((unsigned)Yq < 128u) && ((unsigned)Xq < 128u);
    int q = (n<<14) + (Yq<<7) + Xq;
    g[tap] = v ? sgT[q] : 0ull;
    m[tap] = v ? nzTb[q] : 0ull;
    C += __popcll(m[tap]);
  }
  u64 sg = 0;
  float* rp = r + (size_t)(n*64)*HW + p;
  for (int o=0; o<64; o++){
    const u64* w = &wl[o*9];
    int P = 0;
    #pragma unroll
    for (int tap=0; tap<9; tap++) P += __popcll((g[tap] ^ w[tap]) & m[tap]);
    float rv = rp[(size_t)o*HW] + al[o] * (float)(C - 2*P);   // S2 = C - 2P exactly
    rp[(size_t)o*HW] = rv;
    sg |= (u64)(rv < 0.f) << o;
  }
  sgR[id] = sg;
}

// ---------------- last binary conv + global skip: res = alpha*S + h (in place over h in d_out) ----------------
__global__ __launch_bounds__(256) void k_last(const u64* __restrict__ sgR, const u64* __restrict__ wbits,
                                              const float* __restrict__ alpha, float* __restrict__ res){
  __shared__ u64 wl[576];
  __shared__ float al[64];
  for (int j=threadIdx.x; j<576; j+=256) wl[j] = wbits[j];
  if (threadIdx.x < 64) al[threadIdx.x] = alpha[threadIdx.x];
  __syncthreads();
  const int id = blockIdx.x*256 + threadIdx.x;
  const int n = id >> 14, p = id & 16383;
  const int yy = p >> 7, xx = p & 127;
  u64 g[9], m[9];
  int Vtot = 0;
  #pragma unroll
  for (int tap=0; tap<9; tap++){
    int Yq = yy + tap/3 - 1, Xq = xx + tap%3 - 1;
    bool v = ((unsigned)Yq < 128u) && ((unsigned)Xq < 128u);
    g[tap] = v ? sgR[(n<<14) + (Yq<<7) + Xq] : 0ull;
    m[tap] = v ? ~0ull : 0ull;
    Vtot += v ? 64 : 0;
  }
  for (int o=0; o<64; o++){
    const u64* w = &wl[o*9];
    int P = 0;
    #pragma unroll
    for (int tap=0; tap<9; tap++) P += __popcll((g[tap] ^ w[tap]) & m[tap]);
    size_t q = (size_t)(n*64+o)*HW + p;
    res[q] = al[o] * (float)(Vtot - 2*P) + res[q];   // h was stored here by k_head
  }
}

// ---------------- composed tail (interior X), one row per block ----------------
__global__ __launch_bounds__(128) void k_tail(const float* __restrict__ res, const float* __restrict__ weff,
                                              const float* __restrict__ btail, float* __restrict__ out){
  const int x = threadIdx.x;       // 0..127
  const int Y = blockIdx.x;        // 0..255
  const int n = blockIdx.y;
  const int py = Y & 1, y = Y >> 1;
  const int ey = (Y==0) ? 1 : ((Y==255) ? 2 : 0);
  const float* Ws = weff + (size_t)(((ey*3+1)*2+py)) * 6144;   // ex=1 (interior)
  float acc[3][2] = {{0.f,0.f},{0.f,0.f},{0.f,0.f}};
  for (int ry=0; ry<4; ry++){
    const int yy = y + (py-2) + ry;
    const bool rowv = ((unsigned)yy < 128u);
    const float* Wr = Ws + ry*1536;
    const float* rp = res + (size_t)n*64*HW + yy*128 + x;
    for (int ci=0; ci<64; ci++){
      const float* pp = rp + (size_t)ci*HW;
      float v[5];
      #pragma unroll
      for (int j=0; j<5; j++){
        int xxc = x - 2 + j;
        v[j] = (rowv && (unsigned)xxc < 128u) ? pp[j-2] : 0.f;
      }
      const float* Wc = Wr + ci*24;   // [o][px][rx], uniform address -> scalar loads
      #pragma unroll
      for (int o=0; o<3; o++)
        #pragma unroll
        for (int px=0; px<2; px++)
          #pragma unroll
          for (int rx=0; rx<4; rx++)
            acc[o][px] += Wc[(o*2+px)*4+rx] * v[px+rx];
    }
  }
  const float sh[3] = {114.444f, 111.4605f, 103.02f};
  #pragma unroll
  for (int o=0; o<3; o++){
    #pragma unroll
    for (int px=0; px<2; px++){
      int X = 2*x + px;
      if (X == 0 || X == 255) continue;   // handled by k_border with edge weights
      out[(size_t)((n*3+o)*256+Y)*256 + X] = acc[o][px] + btail[o] + sh[o];
    }
  }
}

// ---------------- tail edge columns X=0 / X=255 ----------------
__global__ __launch_bounds__(256) void k_border(const float* __restrict__ res, const float* __restrict__ weff,
                                                const float* __restrict__ btail, float* __restrict__ out){
  int t = blockIdx.x*256 + threadIdx.x;   // 16*256*2
  if (t >= 8192) return;
  int side = t & 1;
  int Y = (t >> 1) & 255;
  int n = t >> 9;
  int X = side ? 255 : 0;
  int px = side, x = side ? 127 : 0;
  int py = Y & 1, y = Y >> 1;
  int ey = (Y==0) ? 1 : ((Y==255) ? 2 : 0);
  int ex = side ? 2 : 0;
  const float* Ws = weff + (size_t)((ey*3+ex)*2+py) * 6144;
  float acc[3] = {0.f,0.f,0.f};
  for (int ry=0; ry<4; ry++){
    int yy = y + (py-2) + ry;
    bool rowv = ((unsigned)yy < 128u);
    const float* rp = res + (size_t)n*64*HW + yy*128;
    for (int ci=0; ci<64; ci++){
      const float* Wc = Ws + ry*1536 + ci*24 + px*4;
      #pragma unroll
      for (int rx=0; rx<4; rx++){
        int xxc = x + (px-2) + rx;
        float v = (rowv && (unsigned)xxc < 128u) ? rp[(size_t)ci*HW + xxc] : 0.f;
        acc[0] += Wc[0*8+rx] * v;
        acc[1] += Wc[1*8+rx] * v;
        acc[2] += Wc[2*8+rx] * v;
      }
    }
  }
  const float sh[3] = {114.444f, 111.4605f, 103.02f};
  for (int o=0; o<3; o++)
    out[(size_t)((n*3+o)*256+Y)*256 + X] = acc[o] + btail[o] + sh[o];
}

extern "C" void kernel_launch(void* const* d_in, const int* in_sizes, int n_in,
                              void* d_out, int out_size, void* d_ws, size_t ws_size,
                              hipStream_t stream) {
  const float* x      = (const float*)d_in[0];
  const float* w_head = (const float*)d_in[1];
  const float* w_body = (const float*)d_in[2];
  const float* w_last = (const float*)d_in[3];
  const float* w_up   = (const float*)d_in[4];
  const float* w_tail = (const float*)d_in[5];
  const float* b_tail = (const float*)d_in[6];

  char* ws = (char*)d_ws;
  float* r     = (float*)(ws + OFF_R);
  u64*  sgR    = (u64*) (ws + OFF_SGR);
  u64*  sgT    = (u64*) (ws + OFF_SGT);
  u64*  nzT    = (u64*) (ws + OFF_NZT);
  u64*  wbits  = (u64*) (ws + OFF_WBITS);
  float* alpha = (float*)(ws + OFF_ALPHA);
  float* weff  = (float*)(ws + OFF_WEFF);

  float* out = (float*)d_out;        // [16,3,256,256]
  float* res = out + 3145728;        // [16,64,128,128] (output 1; holds h until k_last, then res)

  k_prep_bits<<<9, 256, 0, stream>>>(w_body, w_last, wbits, alpha);
  k_prep_weff<<<432, 256, 0, stream>>>(w_up, w_tail, weff);
  k_head<<<1024, 256, 0, stream>>>(x, w_head, r, res, sgR);
  for (int i=0; i<16; i++){
    k_conv1<<<1024, 256, 0, stream>>>(sgR, wbits + (size_t)(2*i)*576, sgT, nzT);
    k_conv2<<<1024, 256, 0, stream>>>(sgT, nzT, wbits + (size_t)(2*i+1)*576,
                                      alpha + (size_t)(2*i+1)*64, r, sgR);
  }
  k_last<<<1024, 256, 0, stream>>>(sgR, wbits + (size_t)32*576, alpha + 32*64, res);
  k_tail<<<dim3(256,16), 128, 0, stream>>>(res, weff, b_tail, out);
  k_border<<<32, 256, 0, stream>>>(res, weff, b_tail, out);
}

// Round 3
// 1353.347 us; speedup vs baseline: 1.2265x; 1.2265x over previous
//
#include <hip/hip_runtime.h>
#include <stdint.h>

typedef unsigned long long u64;
typedef unsigned int u32;
using i32x4  = __attribute__((ext_vector_type(4))) int;
using i32x16 = __attribute__((ext_vector_type(16))) int;
using f32x4  = __attribute__((ext_vector_type(4))) float;

#define HW 16384   // 128*128

// workspace byte offsets (total ~75.1 MB)
#define OFF_R      0ull           // f32 [16][64][16384] running r
#define OFF_SGR    67108864ull    // u64 [16][16384] sign bits of r
#define OFF_SGT    69206016ull    // u64 [16][16384] sign bits of conv1 sums
#define OFF_NZT    71303168ull    // u64 [16][16384] nonzero bits of conv1 sums
#define OFF_WBSG   73400320ull    // i8  [33][9 tap][64 oc][64 ci] sign weights
#define OFF_ALPHA  74616832ull    // f32 [33][64]
#define OFF_WEFF   74625280ull    // f32 110592 composed tail weights

// ---------------- prep: i8 sign-weight tensor [conv][tap][oc][ci] + alpha ----------------
__global__ __launch_bounds__(256) void k_prep_wbsg(const float* __restrict__ wbody, const float* __restrict__ wlast,
                                                   signed char* __restrict__ wB, float* __restrict__ alpha){
  int t = blockIdx.x*256 + threadIdx.x;          // 33*9*64 = 19008
  if (t >= 33*9*64) return;
  int o = t & 63, tap = (t>>6)%9, cid = t/(64*9);
  const float* src = (cid < 32) ? (wbody + (size_t)cid*36864) : wlast;   // [o][ci][9]
  u32 d[16];
  #pragma unroll
  for (int c4=0;c4<16;c4++){
    u32 v=0;
    #pragma unroll
    for (int j=0;j<4;j++){
      float w = src[(o*64 + c4*4+j)*9 + tap];
      v |= ((w < 0.f) ? 0xFFu : 0x01u) << (8*j);
    }
    d[c4]=v;
  }
  i32x4* dst = (i32x4*)(wB + ((size_t)(cid*9+tap)*64 + o)*64);
  #pragma unroll
  for (int k=0;k<4;k++){ i32x4 v; v[0]=(int)d[4*k]; v[1]=(int)d[4*k+1]; v[2]=(int)d[4*k+2]; v[3]=(int)d[4*k+3]; dst[k]=v; }
  if (tap==0){
    float s=0.f;
    for (int ci=0;ci<64;ci++)
      #pragma unroll
      for (int tp=0;tp<9;tp++) s += fabsf(src[(o*64+ci)*9+tp]);
    alpha[cid*64+o] = s * (1.0f/576.0f);
  }
}

// ------- prep: composed up->shuffle->tail weights (9 edge variants) -------
__global__ __launch_bounds__(256) void k_prep_weff(const float* __restrict__ wup, const float* __restrict__ wtail,
                                                   float* __restrict__ weff){
  int idx = blockIdx.x*256 + threadIdx.x;     // 110592 exactly
  int rx = idx & 3;
  int px = (idx >> 2) & 1;
  int base = idx >> 3;
  int o  = base % 3;
  int t2 = base / 3;
  int ci = t2 & 63;
  int ry = (t2 >> 6) & 3;
  int py = (t2 >> 8) & 1;
  int e  = t2 >> 9;            // 0..8
  int ex = e % 3, ey = e / 3;
  int ry_off = (py - 2) + ry;
  int rx_off = (px - 2) + rx;
  float acc = 0.f;
  for (int dy=0; dy<3; dy++){
    if (ey==1 && dy==0) continue;
    if (ey==2 && dy==2) continue;
    int pydy = py + dy - 1;
    int sy = ((pydy + 4) >> 1) - 2;
    int vy = (pydy + 4) & 1;
    int a = ry_off + 1 - sy;
    if (a < 0 || a > 2) continue;
    for (int dx=0; dx<3; dx++){
      if (ex==0 && dx==0) continue;
      if (ex==2 && dx==2) continue;
      int pxdx = px + dx - 1;
      int sx = ((pxdx + 4) >> 1) - 2;
      int vx = (pxdx + 4) & 1;
      int b = rx_off + 1 - sx;
      if (b < 0 || b > 2) continue;
      for (int c=0; c<64; c++){
        int u = c*4 + vy*2 + vx;
        acc += wtail[((o*64+c)*3+dy)*3+dx] * wup[((u*64+ci)*3+a)*3+b];
      }
    }
  }
  weff[idx] = acc;
}

// ---------------- head: (x - shift) conv 3->64, init r=h (h in d_out res region), pack signs ----------------
__global__ __launch_bounds__(256) void k_head(const float* __restrict__ x, const float* __restrict__ wh,
                                              float* __restrict__ r, float* __restrict__ h, u64* __restrict__ sgR){
  __shared__ float wl[64*27];
  for (int j=threadIdx.x; j<64*27; j+=256) wl[j] = wh[j];
  __syncthreads();
  const int id = blockIdx.x*256 + threadIdx.x;
  const int n = id >> 14, p = id & 16383;
  const int yy = p >> 7, xx = p & 127;
  float xv[27];
  const float sh[3] = {114.444f, 111.4605f, 103.02f};
  #pragma unroll
  for (int tap=0; tap<9; tap++){
    int Yq = yy + tap/3 - 1, Xq = xx + tap%3 - 1;
    bool v = ((unsigned)Yq < 128u) && ((unsigned)Xq < 128u);
    int q = (Yq << 7) + Xq;
    #pragma unroll
    for (int c=0; c<3; c++)
      xv[c*9+tap] = v ? (x[(size_t)(n*3+c)*HW + q] - sh[c]) : 0.f;
  }
  u64 sg = 0;
  for (int o=0; o<64; o++){
    float acc = 0.f;
    #pragma unroll
    for (int j=0; j<27; j++) acc += wl[o*27+j] * xv[j];
    r[(size_t)(n*64+o)*HW + p] = acc;
    h[(size_t)(n*64+o)*HW + p] = acc;
    sg |= (u64)(acc < 0.f) << o;
  }
  sgR[id] = sg;
}

// ---------------- MFMA binary conv: 2 rows x 64 px x 64 oc per block ----------------
// MODE 0: conv1  (in sgR only -> write sgT,nzT chunks)
// MODE 1: conv2  (in sgT,nzT  -> r += alpha*S, write sgR chunks)
// MODE 2: last   (in sgR only -> res += alpha*S; res holds h)
template<int MODE>
__global__ __launch_bounds__(256) void k_bconv(const u64* __restrict__ sgIn, const u64* __restrict__ nzIn,
                                               const signed char* __restrict__ wB, const float* __restrict__ alphaC,
                                               float* __restrict__ rbuf, u64* __restrict__ sgOut,
                                               u64* __restrict__ nzOut, float* __restrict__ resbuf){
  __shared__ signed char Abytes[4*68*80];   // 4 rows x 66(+2 pad) cols x 64 sign-bytes (80B stride)

  const int bx = blockIdx.x;
  const int n  = bx >> 7;
  const int rem = bx & 127;
  const int y0 = (rem >> 1) << 1;     // 0..126 step 2
  const int x0 = (rem & 1) << 6;      // 0 or 64

  const int lane = threadIdx.x & 63;
  const int wid  = threadIdx.x >> 6;
  const int rrow = wid >> 1;          // output row within block (0/1)
  const int och  = wid & 1;           // oc half (0/1)
  const int nn   = lane & 31;
  const int q    = lane >> 5;

  // ---- B fragments (weights) in registers: 9 taps x 2 K-halves ----
  i32x4 Bf[9][2];
  #pragma unroll
  for (int t=0;t<9;t++)
    #pragma unroll
    for (int h=0;h<2;h++)
      Bf[t][h] = *(const i32x4*)(wB + ((size_t)(t*64 + och*32 + nn))*64 + h*32 + q*16);

  // ---- decode sg/nz bits -> i8 sign bytes in LDS (im2col source) ----
  for (int s = threadIdx.x; s < 4*66; s += 256){
    int g = s/66, c = s%66;
    int y = y0 + g - 1, xcol = x0 + c - 1;
    u64 pos=0, neg=0;
    if (((unsigned)y < 128u) && ((unsigned)xcol < 128u)){
      int p = (n<<14) + (y<<7) + xcol;
      u64 sg = sgIn[p];
      if (MODE==1){ u64 nz = nzIn[p]; pos = nz & ~sg; neg = nz & sg; }
      else        { pos = ~sg;        neg = sg; }
    }
    u32 plo=(u32)pos, phi=(u32)(pos>>32), nlo=(u32)neg, nhi=(u32)(neg>>32);
    u32 tmp[16];
    #pragma unroll
    for (int i=0;i<16;i++){
      u32 np = ((i<8) ? (plo >> (4*i)) : (phi >> (4*i-32))) & 0xFu;
      u32 nm = ((i<8) ? (nlo >> (4*i)) : (nhi >> (4*i-32))) & 0xFu;
      u32 bp = (np * 0x00204081u) & 0x01010101u;
      u32 bn = (nm * 0x00204081u) & 0x01010101u;
      tmp[i] = bp | (bn * 0xFFu);
    }
    i32x4* dst = (i32x4*)&Abytes[(g*68 + c)*80];
    #pragma unroll
    for (int k=0;k<4;k++){ i32x4 v; v[0]=(int)tmp[4*k]; v[1]=(int)tmp[4*k+1]; v[2]=(int)tmp[4*k+2]; v[3]=(int)tmp[4*k+3]; dst[k]=v; }
  }
  __syncthreads();

  const float al = (MODE==0) ? 0.f : alphaC[och*32 + nn];

  for (int xh=0; xh<2; xh++){
    i32x16 acc;
    #pragma unroll
    for (int k=0;k<16;k++) acc[k]=0;

    const i32x4* Ap = (const i32x4*)&Abytes[(rrow*68 + xh*32 + nn)*80 + q*16];
    #pragma unroll
    for (int dy=0;dy<3;dy++)
      #pragma unroll
      for (int dx=0;dx<3;dx++){
        const int t = dy*3+dx;
        #pragma unroll
        for (int h=0;h<2;h++){
          i32x4 a = Ap[(dy*68+dx)*5 + h*2];
          acc = __builtin_amdgcn_mfma_i32_32x32x32_i8(a, Bf[t][h], acc, 0, 0, 0);
        }
      }

    // D layout: col(oc)=lane&31, row(px)=(reg&3)+8*(reg>>2)+4*(lane>>5)
    const int ybase = y0 + rrow, xbase = x0 + xh*32;

    if (MODE==0){
      u32 sgc=0, nzc=0;
      #pragma unroll
      for (int reg=0; reg<16; reg++){
        u64 bs = __ballot(acc[reg] < 0);
        u64 bn = __ballot(acc[reg] != 0);
        const int px0 = (reg&3) + ((reg>>2)<<3);
        sgc = (lane==px0  ) ? (u32)bs       : sgc;
        sgc = (lane==px0+4) ? (u32)(bs>>32) : sgc;
        nzc = (lane==px0  ) ? (u32)bn       : nzc;
        nzc = (lane==px0+4) ? (u32)(bn>>32) : nzc;
      }
      if (lane < 32){
        int p = (n<<14) + (ybase<<7) + xbase + lane;
        ((u32*)sgOut)[p*2 + och] = sgc;
        ((u32*)nzOut)[p*2 + och] = nzc;
      }
    } else if (MODE==1){
      float newr[16];
      float* rp = rbuf + ((size_t)((n<<6) + och*32 + nn))*HW + (ybase<<7) + xbase;
      #pragma unroll
      for (int k2=0;k2<4;k2++){
        f32x4 rv = *(f32x4*)(rp + 4*q + 8*k2);
        #pragma unroll
        for (int j=0;j<4;j++){ rv[j] += al * (float)acc[4*k2+j]; newr[4*k2+j] = rv[j]; }
        *(f32x4*)(rp + 4*q + 8*k2) = rv;
      }
      u32 sgc=0;
      #pragma unroll
      for (int reg=0; reg<16; reg++){
        u64 b = __ballot(newr[reg] < 0.f);
        const int px0 = (reg&3) + ((reg>>2)<<3);
        sgc = (lane==px0  ) ? (u32)b       : sgc;
        sgc = (lane==px0+4) ? (u32)(b>>32) : sgc;
      }
      if (lane < 32){
        int p = (n<<14) + (ybase<<7) + xbase + lane;
        ((u32*)sgOut)[p*2 + och] = sgc;
      }
    } else {
      float* hp = resbuf + ((size_t)((n<<6) + och*32 + nn))*HW + (ybase<<7) + xbase;
      #pragma unroll
      for (int k2=0;k2<4;k2++){
        f32x4 hv = *(f32x4*)(hp + 4*q + 8*k2);
        #pragma unroll
        for (int j=0;j<4;j++) hv[j] += al * (float)acc[4*k2+j];
        *(f32x4*)(hp + 4*q + 8*k2) = hv;
      }
    }
  }
}

// ---------------- composed tail (interior X), one row per block ----------------
__global__ __launch_bounds__(128) void k_tail(const float* __restrict__ res, const float* __restrict__ weff,
                                              const float* __restrict__ btail, float* __restrict__ out){
  const int x = threadIdx.x;       // 0..127
  const int Y = blockIdx.x;        // 0..255
  const int n = blockIdx.y;
  const int py = Y & 1, y = Y >> 1;
  const int ey = (Y==0) ? 1 : ((Y==255) ? 2 : 0);
  const float* Ws = weff + (size_t)(((ey*3+1)*2+py)) * 6144;   // ex=1 (interior)
  float acc[3][2] = {{0.f,0.f},{0.f,0.f},{0.f,0.f}};
  for (int ry=0; ry<4; ry++){
    const int yy = y + (py-2) + ry;
    const bool rowv = ((unsigned)yy < 128u);
    const float* Wr = Ws + ry*1536;
    const float* rp = res + (size_t)n*64*HW + yy*128 + x;
    for (int ci=0; ci<64; ci++){
      const float* pp = rp + (size_t)ci*HW;
      float v[5];
      #pragma unroll
      for (int j=0; j<5; j++){
        int xxc = x - 2 + j;
        v[j] = (rowv && (unsigned)xxc < 128u) ? pp[j-2] : 0.f;
      }
      const float* Wc = Wr + ci*24;
      #pragma unroll
      for (int o=0; o<3; o++)
        #pragma unroll
        for (int px=0; px<2; px++)
          #pragma unroll
          for (int rx=0; rx<4; rx++)
            acc[o][px] += Wc[(o*2+px)*4+rx] * v[px+rx];
    }
  }
  const float sh[3] = {114.444f, 111.4605f, 103.02f};
  #pragma unroll
  for (int o=0; o<3; o++){
    #pragma unroll
    for (int px=0; px<2; px++){
      int X = 2*x + px;
      if (X == 0 || X == 255) continue;
      out[(size_t)((n*3+o)*256+Y)*256 + X] = acc[o][px] + btail[o] + sh[o];
    }
  }
}

// ---------------- tail edge columns X=0 / X=255 ----------------
__global__ __launch_bounds__(256) void k_border(const float* __restrict__ res, const float* __restrict__ weff,
                                                const float* __restrict__ btail, float* __restrict__ out){
  int t = blockIdx.x*256 + threadIdx.x;   // 16*256*2
  if (t >= 8192) return;
  int side = t & 1;
  int Y = (t >> 1) & 255;
  int n = t >> 9;
  int X = side ? 255 : 0;
  int px = side, x = side ? 127 : 0;
  int py = Y & 1, y = Y >> 1;
  int ey = (Y==0) ? 1 : ((Y==255) ? 2 : 0);
  int ex = side ? 2 : 0;
  const float* Ws = weff + (size_t)((ey*3+ex)*2+py) * 6144;
  float acc[3] = {0.f,0.f,0.f};
  for (int ry=0; ry<4; ry++){
    int yy = y + (py-2) + ry;
    bool rowv = ((unsigned)yy < 128u);
    const float* rp = res + (size_t)n*64*HW + yy*128;
    for (int ci=0; ci<64; ci++){
      const float* Wc = Ws + ry*1536 + ci*24 + px*4;
      #pragma unroll
      for (int rx=0; rx<4; rx++){
        int xxc = x + (px-2) + rx;
        float v = (rowv && (unsigned)xxc < 128u) ? rp[(size_t)ci*HW + xxc] : 0.f;
        acc[0] += Wc[0*8+rx] * v;
        acc[1] += Wc[1*8+rx] * v;
        acc[2] += Wc[2*8+rx] * v;
      }
    }
  }
  const float sh[3] = {114.444f, 111.4605f, 103.02f};
  for (int o=0; o<3; o++)
    out[(size_t)((n*3+o)*256+Y)*256 + X] = acc[o] + btail[o] + sh[o];
}

extern "C" void kernel_launch(void* const* d_in, const int* in_sizes, int n_in,
                              void* d_out, int out_size, void* d_ws, size_t ws_size,
                              hipStream_t stream) {
  const float* x      = (const float*)d_in[0];
  const float* w_head = (const float*)d_in[1];
  const float* w_body = (const float*)d_in[2];
  const float* w_last = (const float*)d_in[3];
  const float* w_up   = (const float*)d_in[4];
  const float* w_tail = (const float*)d_in[5];
  const float* b_tail = (const float*)d_in[6];

  char* ws = (char*)d_ws;
  float* r     = (float*)(ws + OFF_R);
  u64*  sgR    = (u64*) (ws + OFF_SGR);
  u64*  sgT    = (u64*) (ws + OFF_SGT);
  u64*  nzT    = (u64*) (ws + OFF_NZT);
  signed char* wBsg = (signed char*)(ws + OFF_WBSG);
  float* alpha = (float*)(ws + OFF_ALPHA);
  float* weff  = (float*)(ws + OFF_WEFF);

  float* out = (float*)d_out;        // [16,3,256,256]
  float* res = out + 3145728;        // [16,64,128,128] (holds h until k_bconv<2>, then res)

  k_prep_wbsg<<<75, 256, 0, stream>>>(w_body, w_last, wBsg, alpha);
  k_prep_weff<<<432, 256, 0, stream>>>(w_up, w_tail, weff);
  k_head<<<1024, 256, 0, stream>>>(x, w_head, r, res, sgR);
  for (int i=0; i<16; i++){
    k_bconv<0><<<2048, 256, 0, stream>>>(sgR, nullptr, wBsg + (size_t)(2*i)*36864,
                                         nullptr, nullptr, sgT, nzT, nullptr);
    k_bconv<1><<<2048, 256, 0, stream>>>(sgT, nzT, wBsg + (size_t)(2*i+1)*36864,
                                         alpha + (2*i+1)*64, r, sgR, nullptr, nullptr);
  }
  k_bconv<2><<<2048, 256, 0, stream>>>(sgR, nullptr, wBsg + (size_t)32*36864,
                                       alpha + 32*64, nullptr, nullptr, nullptr, res);
  k_tail<<<dim3(256,16), 128, 0, stream>>>(res, weff, b_tail, out);
  k_border<<<32, 256, 0, stream>>>(res, weff, b_tail, out);
}